// Round 8
// baseline (1943.941 us; speedup 1.0000x reference)
//
#include <hip/hip_runtime.h>

// Problem constants
#define BB   512
#define CC   22
#define TT   1000
#define HH   64
#define NCLS 4
#define MB   4            // batch rows per wave/block
#define NBLK (BB / MB)    // 128 blocks, 1 wave each -> 1 block per CU on half the chip
#define RS   72           // ring row stride in f16 (144 B: conflict-free A reads)
#define SS   (4 * RS)     // ring slot stride in f16 (288)

typedef _Float16 f16;
typedef __attribute__((ext_vector_type(8))) _Float16 f16x8;
typedef __attribute__((ext_vector_type(4))) float    f32x4;

union F8U { f16x8 v; uint4 u; f16 h[8]; };

__device__ __forceinline__ float sigm(float x) { return 1.0f / (1.0f + __expf(-x)); }
__device__ __forceinline__ float tanh_(float x) {
    float e = __expf(-2.0f * fabsf(x));   // (0,1], no overflow
    float r = (1.0f - e) / (1.0f + e);
    return copysignf(r, x);
}

// One wave per 4 batch rows, zero barriers. Per step:
//   D[16][256] = A(16x96)·B(96x256): A rows = batch replicated x4 (batch=m>>2),
//   B = W^T resident in AGPRs (192 regs, MFMA reads in place — R7-proven).
// D layout (col=lane&15, row=4q+i -> batch=q): lane (q,c) owns batch q,
// hids {16j+c} -> 4 UNIQUE cell updates per lane (R7 wasted 94% of MFMA and
// 4x the epilogue on batch=1; this serves 4 rows for the same 48 MFMAs).
// x is read per-step straight from global (broadcast loads, L1-resident
// lines, prefetched 1 step ahead; independent of the h chain). h lives in an
// 8-slot LDS ring (144B row stride -> conflict-free reads), dumped to global
// coalesced every 8 steps; FC+softmax is the R7-validated second kernel.
__global__
__attribute__((amdgpu_flat_work_group_size(64, 64), amdgpu_waves_per_eu(1, 1)))
void lstm_mfma4(
    const float* __restrict__ x,     // [B, C, T]
    const float* __restrict__ W_ih,  // [4H, C]
    const float* __restrict__ W_hh,  // [4H, H]
    const float* __restrict__ b_ih,  // [4H]
    const float* __restrict__ b_hh,  // [4H]
    f16* __restrict__ hglob)         // [B, T*H] workspace
{
    __shared__ __align__(16) f16 ring[8 * SS];   // 4.6 KB: h ring, 8 slots

    const int lane = threadIdx.x;
    const int q    = lane >> 4;          // B k-block / D row-quad (= epilogue batch)
    const int c    = lane & 15;          // B col within tile / D col
    const int ab   = (lane & 15) >> 2;   // A-operand batch  (A row m = lane&15)
    const int b0   = blockIdx.x * MB;

    // ---- one-time: B fragments (weights -> AGPRs) + bias ----
    // B[k][n]: lane holds B[k=8q+j][n=c] of each 16-gate tile; 3 k-frags.
    f16x8 Bh0[16], Bh1[16], Bx[16];
    float bias_s[16];
    #pragma unroll
    for (int n = 0; n < 16; ++n) {
        const int g = 16 * n + c;        // gate row
        F8U a, b, cc;
        const float* wr = W_hh + g * HH + 8 * q;
        #pragma unroll
        for (int j = 0; j < 8; ++j) { a.h[j] = (f16)wr[j]; b.h[j] = (f16)wr[32 + j]; }
        #pragma unroll
        for (int j = 0; j < 8; ++j) {
            const int ch = 8 * q + j;
            cc.h[j] = (ch < CC) ? (f16)W_ih[g * CC + ch] : (f16)0.f;
        }
        Bh0[n] = a.v; Bh1[n] = b.v; Bx[n] = cc.v;
        bias_s[n] = b_ih[g] + b_hh[g];
    }

    // h(-1) = 0 in ring slot 7
    for (int i = lane; i < SS; i += 64) ring[7 * SS + i] = (f16)0.f;

    // x source for this lane's A fragment: batch b0+ab, channels 8q..8q+7
    const float* xb = x + (size_t)(b0 + ab) * (CC * TT);
    F8U Ax;
    #pragma unroll
    for (int j = 0; j < 8; ++j) {
        const int ch = 8 * q + j;
        float v = 0.f;
        if (ch < CC) v = xb[ch * TT];    // t = 0
        Ax.h[j] = (f16)v;
    }

    float cst[4] = {0.f, 0.f, 0.f, 0.f};    // cell state: batch q, hids 16j+c

    for (int t8 = 0; t8 < TT / 8; ++t8) {
        #pragma unroll
        for (int s = 0; s < 8; ++s) {
            const int t  = t8 * 8 + s;
            const int sp = (s + 7) & 7;      // previous step's ring slot

            // x-part MFMAs first: independent of the h ring read
            const f32x4 z = {0.f, 0.f, 0.f, 0.f};
            f32x4 acc[16];
            #pragma unroll
            for (int n = 0; n < 16; ++n)
                acc[n] = __builtin_amdgcn_mfma_f32_16x16x32_f16(Ax.v, Bx[n], z, 0, 0, 0);

            // h A-frags from ring (broadcast within 4-lane dup groups)
            F8U Ah0, Ah1;
            Ah0.u = *(const uint4*)&ring[sp * SS + ab * RS + 8 * q];
            Ah1.u = *(const uint4*)&ring[sp * SS + ab * RS + 32 + 8 * q];
            #pragma unroll
            for (int n = 0; n < 16; ++n)
                acc[n] = __builtin_amdgcn_mfma_f32_16x16x32_f16(Ah0.v, Bh0[n], acc[n], 0, 0, 0);
            #pragma unroll
            for (int n = 0; n < 16; ++n)
                acc[n] = __builtin_amdgcn_mfma_f32_16x16x32_f16(Ah1.v, Bh1[n], acc[n], 0, 0, 0);

            // prefetch x for t+1 (issues under the MFMA/epilogue latency)
            {
                const int tn = (t < TT - 1) ? t + 1 : 0;
                F8U nx;
                #pragma unroll
                for (int j = 0; j < 8; ++j) {
                    const int ch = 8 * q + j;
                    float v = 0.f;
                    if (ch < CC) v = xb[ch * TT + tn];
                    nx.h[j] = (f16)v;
                }
                Ax = nx;
            }

            // ---- epilogue: 4 unique cell updates (batch q, hid 16j+c) ----
            // gate G of hid 16j+c is acc[4G+j][i] (i regs duplicated; use [0])
            #pragma unroll
            for (int j = 0; j < 4; ++j) {
                float iv = sigm (acc[j][0]      + bias_s[j]);
                float fv = sigm (acc[4 + j][0]  + bias_s[4 + j]);
                float gv = tanh_(acc[8 + j][0]  + bias_s[8 + j]);
                float ov = sigm (acc[12 + j][0] + bias_s[12 + j]);
                cst[j] = fv * cst[j] + iv * gv;
                float h = ov * tanh_(cst[j]);
                ring[s * SS + q * RS + 16 * j + c] = (f16)h;   // batch q's row
            }
        }

        // ---- dump 8 steps of h to global, coalesced (reads precede the
        //      next group's ring writes in-order on the DS pipe) ----
        const int t0 = t8 * 8;
        #pragma unroll
        for (int i = 0; i < 4; ++i) {
            const int idx = lane + 64 * i;          // 0..255
            const int ss  = idx >> 5;               // ring slot 0..7
            const int bb  = (idx >> 3) & 3;         // batch row
            const int h8  = (idx & 7) * 8;          // hid block
            uint4 v = *(const uint4*)&ring[ss * SS + bb * RS + h8];
            *(uint4*)&hglob[((size_t)(b0 + bb) * TT + t0 + ss) * HH + h8] = v;
        }
    }
}

// FC + softmax (R7-validated): logits[B][4] = h_all[B][64000]·W_fc^T + b_fc.
__global__ __launch_bounds__(256) void fc_softmax(
    const f16*  __restrict__ hglob,  // [B, T*H]
    const float* __restrict__ W_fc,  // [NCLS, T*H]
    const float* __restrict__ b_fc,  // [NCLS]
    float* __restrict__ out)         // [B, NCLS]
{
    const int w    = threadIdx.x >> 6;
    const int lane = threadIdx.x & 63;
    const int r    = blockIdx.x * 4 + w;

    const f16* hr = hglob + (size_t)r * (TT * HH);
    float a0 = 0.f, a1 = 0.f, a2 = 0.f, a3 = 0.f;

    for (int i = 0; i < (TT * HH) / 512; ++i) {     // 125 iters
        const int k = i * 512 + lane * 8;
        F8U hv; hv.u = *(const uint4*)&hr[k];
        float hf[8];
        #pragma unroll
        for (int j = 0; j < 8; ++j) hf[j] = (float)hv.h[j];

        const float* w0 = W_fc + 0 * (TT * HH) + k;
        const float* w1 = W_fc + 1 * (TT * HH) + k;
        const float* w2 = W_fc + 2 * (TT * HH) + k;
        const float* w3 = W_fc + 3 * (TT * HH) + k;
        float4 v0a = *(const float4*)w0, v0b = *(const float4*)(w0 + 4);
        float4 v1a = *(const float4*)w1, v1b = *(const float4*)(w1 + 4);
        float4 v2a = *(const float4*)w2, v2b = *(const float4*)(w2 + 4);
        float4 v3a = *(const float4*)w3, v3b = *(const float4*)(w3 + 4);

        a0 += hf[0]*v0a.x + hf[1]*v0a.y + hf[2]*v0a.z + hf[3]*v0a.w
            + hf[4]*v0b.x + hf[5]*v0b.y + hf[6]*v0b.z + hf[7]*v0b.w;
        a1 += hf[0]*v1a.x + hf[1]*v1a.y + hf[2]*v1a.z + hf[3]*v1a.w
            + hf[4]*v1b.x + hf[5]*v1b.y + hf[6]*v1b.z + hf[7]*v1b.w;
        a2 += hf[0]*v2a.x + hf[1]*v2a.y + hf[2]*v2a.z + hf[3]*v2a.w
            + hf[4]*v2b.x + hf[5]*v2b.y + hf[6]*v2b.z + hf[7]*v2b.w;
        a3 += hf[0]*v3a.x + hf[1]*v3a.y + hf[2]*v3a.z + hf[3]*v3a.w
            + hf[4]*v3b.x + hf[5]*v3b.y + hf[6]*v3b.z + hf[7]*v3b.w;
    }

    #pragma unroll
    for (int off = 32; off; off >>= 1) {
        a0 += __shfl_down(a0, off);
        a1 += __shfl_down(a1, off);
        a2 += __shfl_down(a2, off);
        a3 += __shfl_down(a3, off);
    }
    if (lane == 0) {
        float l0 = a0 + b_fc[0], l1 = a1 + b_fc[1];
        float l2 = a2 + b_fc[2], l3 = a3 + b_fc[3];
        float m  = fmaxf(fmaxf(l0, l1), fmaxf(l2, l3));
        float e0 = __expf(l0 - m), e1 = __expf(l1 - m);
        float e2 = __expf(l2 - m), e3 = __expf(l3 - m);
        float s  = e0 + e1 + e2 + e3;
        float4 o; o.x = e0 / s; o.y = e1 / s; o.z = e2 / s; o.w = e3 / s;
        *(float4*)(out + r * NCLS) = o;
    }
}

extern "C" void kernel_launch(void* const* d_in, const int* in_sizes, int n_in,
                              void* d_out, int out_size, void* d_ws, size_t ws_size,
                              hipStream_t stream) {
    const float* x    = (const float*)d_in[0];
    const float* W_ih = (const float*)d_in[1];
    const float* W_hh = (const float*)d_in[2];
    const float* b_ih = (const float*)d_in[3];
    const float* b_hh = (const float*)d_in[4];
    const float* W_fc = (const float*)d_in[5];
    const float* b_fc = (const float*)d_in[6];
    float* out = (float*)d_out;
    f16*  hglob = (f16*)d_ws;        // 512*64000*2 = 65.54 MB (fit proven in R7)

    lstm_mfma4<<<NBLK, 64, 0, stream>>>(x, W_ih, W_hh, b_ih, b_hh, hglob);
    fc_softmax<<<BB / 4, 256, 0, stream>>>(hglob, W_fc, b_fc, out);
}

// Round 9
// 765.938 us; speedup vs baseline: 2.5380x; 2.5380x over previous
//
#include <hip/hip_runtime.h>

// Problem constants
#define BB   512
#define CC   22
#define TT   1000
#define HH   64
#define NCLS 4
#define TC   250
#define NCHUNK (TT / TC)

// smem layout (dword offsets within one array => everything may-alias,
// which blocks LICM from hoisting the per-step W_ih reads into registers)
#define OFF_H   0            // 32 dw: h pairs (64 f16)
#define OFF_WT  32           // 3*256*4 = 3072 dw: W_ih transposed frags
#define OFF_XS  (32 + 3072)  // 250*12 = 3000 dw: x chunk (12 pairs/step)
#define SMEM_DW (32 + 3072 + 3000)

typedef _Float16 f16;
typedef __attribute__((ext_vector_type(2))) _Float16 h2;

union PU { unsigned u; h2 h; };
union QU { uint4 q; unsigned u[4]; f16 h[8]; };

__device__ __forceinline__ float sigm(float x) { return 1.0f / (1.0f + __expf(-x)); }
__device__ __forceinline__ float tanh_(float x) {
    float e = __expf(-2.0f * fabsf(x));   // (0,1], no overflow
    float r = (1.0f - e) / (1.0f + e);
    return copysignf(r, x);
}
__device__ __forceinline__ h2 u2h(unsigned u) { PU p; p.u = u; return p.h; }

// One wave per batch row; lane = hidden unit; all 4 gates per lane via
// v_dot2_f32_f16; zero barriers (in-wave DS ordering only) — R3 structure.
// R9: register demand pushed under the ~240-reg storm cliff (8-round
// evidence: demand>~250 => per-step refill storm; R5 at ~120 was clean):
//  - W_ih streamed from LDS per step (12 conflict-free ds_read_b128, hidden
//    under the fdot2 issue phase on the VALU pipe),
//  - FC unfused (h stored f16-coalesced to global; kernel 2 does FC+softmax),
//  - H broadcast read in 2 batches of 4 b128 to cap transient pressure.
// Persistent regs: whh 128 + ~15 misc; peak ~200.
__global__
__attribute__((amdgpu_flat_work_group_size(64, 64), amdgpu_waves_per_eu(1, 1)))
void lstm_row(
    const float* __restrict__ x,     // [B, C, T]
    const float* __restrict__ W_ih,  // [4H, C]
    const float* __restrict__ W_hh,  // [4H, H]
    const float* __restrict__ b_ih,  // [4H]
    const float* __restrict__ b_hh,  // [4H]
    f16* __restrict__ hglob)         // [B, T*H] workspace
{
    __shared__ __align__(16) unsigned smem[SMEM_DW];

    const int lane = threadIdx.x;    // hidden unit
    const int r    = blockIdx.x;     // batch row

    // ---- persistent: W_hh rows (f16 pairs) for gates i,f,g,o: 128 regs ----
    unsigned whh[4][32];
    float bias[4];
    #pragma unroll
    for (int g = 0; g < 4; ++g) {
        const int row = g * HH + lane;
        const float* wr = W_hh + row * HH;
        #pragma unroll
        for (int k = 0; k < 32; ++k) {
            PU p; p.h = h2{(f16)wr[2 * k], (f16)wr[2 * k + 1]};
            whh[g][k] = p.u;
        }
        bias[g] = b_ih[row] + b_hh[row];
    }

    // ---- one-time: W_ih -> LDS transposed frags wT4[k4][gate] (uint4 of
    //      channel-pairs 4k4..4k4+3; channels >=22 zero) ----
    #pragma unroll
    for (int G = 0; G < 4; ++G) {
        const int g = G * 64 + lane;
        const float* wi = W_ih + g * CC;
        #pragma unroll
        for (int k4 = 0; k4 < 3; ++k4) {
            QU q;
            #pragma unroll
            for (int j = 0; j < 4; ++j) {
                const int c0 = 8 * k4 + 2 * j;
                float lo = (c0     < CC) ? wi[c0]     : 0.f;
                float hi = (c0 + 1 < CC) ? wi[c0 + 1] : 0.f;
                PU p; p.h = h2{(f16)lo, (f16)hi};
                q.u[j] = p.u;
            }
            *(uint4*)&smem[OFF_WT + (k4 * 256 + g) * 4] = q.q;
        }
    }

    ((f16*)smem)[lane] = (f16)0.f;   // h(-1); in-wave ordering suffices

    float c = 0.f;
    const float* xrow = x + (size_t)r * (CC * TT);
    f16* hout = hglob + (size_t)r * (TT * HH) + lane;

    for (int chunk = 0; chunk < NCHUNK; ++chunk) {
        // ---- stage x chunk as 12 f16-pairs/step (11 real + 1 zero pad) ----
        for (int t0 = 0; t0 < TC; t0 += 64) {
            const int t = t0 + lane;
            if (t < TC) {
                const float* gx = xrow + chunk * TC + t;   // channel stride TT
                QU A, Bq, Cq;
                #pragma unroll
                for (int j = 0; j < 4; ++j) {
                    PU p; p.h = h2{(f16)gx[(2*j)*TT], (f16)gx[(2*j+1)*TT]};
                    A.u[j] = p.u;
                }
                #pragma unroll
                for (int j = 0; j < 4; ++j) {
                    PU p; p.h = h2{(f16)gx[(8+2*j)*TT], (f16)gx[(9+2*j)*TT]};
                    Bq.u[j] = p.u;
                }
                #pragma unroll
                for (int j = 0; j < 3; ++j) {
                    PU p; p.h = h2{(f16)gx[(16+2*j)*TT], (f16)gx[(17+2*j)*TT]};
                    Cq.u[j] = p.u;
                }
                Cq.u[3] = 0u;    // pair 11 pad
                uint4* dst = (uint4*)&smem[OFF_XS + t * 12];
                dst[0] = A.q; dst[1] = Bq.q; dst[2] = Cq.q;
            }
        }
        // no barrier: single-wave block, DS pipe is in-order

        for (int tt = 0; tt < TC; ++tt) {
            // ---- H reads FIRST (they head the in-order DS queue => h RT
            //      latency is minimal on the chain) ----
            union { uint4 q[4]; unsigned u[16]; } Ha, Hb;
            const uint4* hp = (const uint4*)&smem[OFF_H];
            Ha.q[0] = hp[0]; Ha.q[1] = hp[1]; Ha.q[2] = hp[2]; Ha.q[3] = hp[3];

            // x pairs for this step (broadcast b128)
            union { uint4 q[3]; unsigned u[12]; } X;
            const uint4* xp = (const uint4*)&smem[OFF_XS + tt * 12];
            X.q[0] = xp[0]; X.q[1] = xp[1]; X.q[2] = xp[2];

            // ---- x-part dots: W_ih frags streamed from LDS per gate ----
            float a0 = bias[0], a1 = bias[1], a2 = bias[2], a3 = bias[3];
            {
                uint4 wf0, wf1, wf2;
                #pragma unroll
                for (int G = 0; G < 4; ++G) {
                    wf0 = *(const uint4*)&smem[OFF_WT + (0 * 256 + G * 64 + lane) * 4];
                    wf1 = *(const uint4*)&smem[OFF_WT + (1 * 256 + G * 64 + lane) * 4];
                    wf2 = *(const uint4*)&smem[OFF_WT + (2 * 256 + G * 64 + lane) * 4];
                    QU w0; w0.q = wf0;  QU w1; w1.q = wf1;  QU w2; w2.q = wf2;
                    float a = (G == 0) ? a0 : (G == 1) ? a1 : (G == 2) ? a2 : a3;
                    #pragma unroll
                    for (int j = 0; j < 4; ++j) a = __builtin_amdgcn_fdot2(u2h(X.u[j]),     u2h(w0.u[j]), a, false);
                    #pragma unroll
                    for (int j = 0; j < 4; ++j) a = __builtin_amdgcn_fdot2(u2h(X.u[4 + j]), u2h(w1.u[j]), a, false);
                    #pragma unroll
                    for (int j = 0; j < 4; ++j) a = __builtin_amdgcn_fdot2(u2h(X.u[8 + j]), u2h(w2.u[j]), a, false);
                    if (G == 0) a0 = a; else if (G == 1) a1 = a; else if (G == 2) a2 = a; else a3 = a;
                }
            }

            // ---- h-part dots: first 16 pairs ----
            #pragma unroll
            for (int k = 0; k < 16; ++k) {
                h2 hv = u2h(Ha.u[k]);
                a0 = __builtin_amdgcn_fdot2(hv, u2h(whh[0][k]), a0, false);
                a1 = __builtin_amdgcn_fdot2(hv, u2h(whh[1][k]), a1, false);
                a2 = __builtin_amdgcn_fdot2(hv, u2h(whh[2][k]), a2, false);
                a3 = __builtin_amdgcn_fdot2(hv, u2h(whh[3][k]), a3, false);
            }
            // second half of H (separate batch caps transient pressure)
            Hb.q[0] = hp[4]; Hb.q[1] = hp[5]; Hb.q[2] = hp[6]; Hb.q[3] = hp[7];
            #pragma unroll
            for (int k = 0; k < 16; ++k) {
                h2 hv = u2h(Hb.u[k]);
                a0 = __builtin_amdgcn_fdot2(hv, u2h(whh[0][16 + k]), a0, false);
                a1 = __builtin_amdgcn_fdot2(hv, u2h(whh[1][16 + k]), a1, false);
                a2 = __builtin_amdgcn_fdot2(hv, u2h(whh[2][16 + k]), a2, false);
                a3 = __builtin_amdgcn_fdot2(hv, u2h(whh[3][16 + k]), a3, false);
            }

            // ---- lane-local LSTM update ----
            float iv = sigm(a0), fv = sigm(a1), gv = tanh_(a2), ov = sigm(a3);
            c = fv * c + iv * gv;
            float h = ov * tanh_(c);

            // publish h (in-wave LDS; single buffer safe) + coalesced dump
            f16 hf = (f16)h;
            ((f16*)smem)[lane] = hf;
            hout[(chunk * TC + tt) * HH] = hf;   // 128 B/wave, store-and-forget
        }
    }
}

// FC + softmax. 32 blocks x 4 waves; each wave handles 4 batch rows so W_fc
// is re-read only 32x (R7's version re-read it 128x -> ~87 us; this ~25 us).
__global__ __launch_bounds__(256) void fc_softmax16(
    const f16*  __restrict__ hglob,  // [B, T*H]
    const float* __restrict__ W_fc,  // [NCLS, T*H]
    const float* __restrict__ b_fc,  // [NCLS]
    float* __restrict__ out)         // [B, NCLS]
{
    const int w    = threadIdx.x >> 6;
    const int lane = threadIdx.x & 63;
    const int r0   = blockIdx.x * 16 + w * 4;

    const f16* hr0 = hglob + (size_t)(r0 + 0) * (TT * HH);
    const f16* hr1 = hglob + (size_t)(r0 + 1) * (TT * HH);
    const f16* hr2 = hglob + (size_t)(r0 + 2) * (TT * HH);
    const f16* hr3 = hglob + (size_t)(r0 + 3) * (TT * HH);

    float acc[4][4] = {{0.f}};   // [row][class]

    for (int i = 0; i < (TT * HH) / 512; ++i) {      // 125 iters
        const int k = i * 512 + lane * 8;

        float4 wa[4], wb[4];
        #pragma unroll
        for (int cl = 0; cl < 4; ++cl) {
            const float* wp = W_fc + (size_t)cl * (TT * HH) + k;
            wa[cl] = *(const float4*)wp;
            wb[cl] = *(const float4*)(wp + 4);
        }
        QU hv[4];
        hv[0].q = *(const uint4*)&hr0[k];
        hv[1].q = *(const uint4*)&hr1[k];
        hv[2].q = *(const uint4*)&hr2[k];
        hv[3].q = *(const uint4*)&hr3[k];

        #pragma unroll
        for (int rr = 0; rr < 4; ++rr) {
            float hf[8];
            #pragma unroll
            for (int j = 0; j < 8; ++j) hf[j] = (float)hv[rr].h[j];
            #pragma unroll
            for (int cl = 0; cl < 4; ++cl) {
                acc[rr][cl] += hf[0]*wa[cl].x + hf[1]*wa[cl].y + hf[2]*wa[cl].z + hf[3]*wa[cl].w
                             + hf[4]*wb[cl].x + hf[5]*wb[cl].y + hf[6]*wb[cl].z + hf[7]*wb[cl].w;
            }
        }
    }

    #pragma unroll
    for (int rr = 0; rr < 4; ++rr)
        #pragma unroll
        for (int cl = 0; cl < 4; ++cl)
            #pragma unroll
            for (int off = 32; off; off >>= 1)
                acc[rr][cl] += __shfl_down(acc[rr][cl], off);

    if (lane == 0) {
        #pragma unroll
        for (int rr = 0; rr < 4; ++rr) {
            float l0 = acc[rr][0] + b_fc[0], l1 = acc[rr][1] + b_fc[1];
            float l2 = acc[rr][2] + b_fc[2], l3 = acc[rr][3] + b_fc[3];
            float m  = fmaxf(fmaxf(l0, l1), fmaxf(l2, l3));
            float e0 = __expf(l0 - m), e1 = __expf(l1 - m);
            float e2 = __expf(l2 - m), e3 = __expf(l3 - m);
            float s  = e0 + e1 + e2 + e3;
            float4 o; o.x = e0 / s; o.y = e1 / s; o.z = e2 / s; o.w = e3 / s;
            *(float4*)(out + (r0 + rr) * NCLS) = o;
        }
    }
}

extern "C" void kernel_launch(void* const* d_in, const int* in_sizes, int n_in,
                              void* d_out, int out_size, void* d_ws, size_t ws_size,
                              hipStream_t stream) {
    const float* x    = (const float*)d_in[0];
    const float* W_ih = (const float*)d_in[1];
    const float* W_hh = (const float*)d_in[2];
    const float* b_ih = (const float*)d_in[3];
    const float* b_hh = (const float*)d_in[4];
    const float* W_fc = (const float*)d_in[5];
    const float* b_fc = (const float*)d_in[6];
    float* out = (float*)d_out;
    f16*  hglob = (f16*)d_ws;        // 512*64000*2 = 65.54 MB (fits, R7/R8)

    lstm_row<<<BB, 64, 0, stream>>>(x, W_ih, W_hh, b_ih, b_hh, hglob);
    fc_softmax16<<<BB / 16, 256, 0, stream>>>(hglob, W_fc, b_fc, out);
}